// Round 1
// baseline (68.421 us; speedup 1.0000x reference)
//
#include <hip/hip_runtime.h>
#include <math.h>

// Luong attention fused single-pass:
//   scores[b,t] = dec[b] . enc[b,t,:]   (D=256)
//   align = softmax_T(scores)
//   out[b,:] = sum_t align[b,t] * enc[b,t,:]
// Online-softmax so enc is read exactly ONCE (268 MB -> ~43us roofline).

#define WAVES_PER_BLOCK 4
#define BLOCK 256
#define D 256

// Kernel 1: per-(batch,chunk) partial with online softmax.
// ws layout: acc[B*P][256] floats, then interleaved (m,l)[B*P][2].
__global__ __launch_bounds__(BLOCK) void attn_partial(
    const float* __restrict__ enc,   // [B,T,D]
    const float* __restrict__ dec,   // [B,D]
    float* __restrict__ ws,
    int T, int P, int nblk_total)
{
    const int blk   = blockIdx.x;
    const int b     = blk / P;
    const int chunk = blk % P;
    const int tid   = threadIdx.x;
    const int wave  = tid >> 6;
    const int lane  = tid & 63;

    const int rows_per_block = T / P;
    const int rows_per_wave  = rows_per_block / WAVES_PER_BLOCK;
    const int t0 = chunk * rows_per_block + wave * rows_per_wave;

    const float* __restrict__ encb = enc + (size_t)b * T * D;

    // dec fragment for this lane's 4 columns (reused every row)
    const float4 dq = *reinterpret_cast<const float4*>(dec + b * D + lane * 4);

    float  m = -INFINITY;
    float  l = 0.0f;
    float4 acc = {0.0f, 0.0f, 0.0f, 0.0f};

    for (int r = 0; r < rows_per_wave; ++r) {
        const int t = t0 + r;
        const float4 x = *reinterpret_cast<const float4*>(encb + (size_t)t * D + lane * 4);
        // partial dot over this lane's 4 columns
        float p = dq.x * x.x + dq.y * x.y + dq.z * x.z + dq.w * x.w;
        // 64-lane butterfly reduce -> full score broadcast to all lanes
        #pragma unroll
        for (int off = 32; off >= 1; off >>= 1)
            p += __shfl_xor(p, off, 64);
        // online softmax update
        const float mn    = fmaxf(m, p);
        const float scale = __expf(m - mn);   // 0 when m == -inf
        const float w     = __expf(p - mn);
        acc.x = acc.x * scale + w * x.x;
        acc.y = acc.y * scale + w * x.y;
        acc.z = acc.z * scale + w * x.z;
        acc.w = acc.w * scale + w * x.w;
        l = l * scale + w;
        m = mn;
    }

    // combine the 4 waves' partials in LDS -> one partial per block
    __shared__ float s_acc[WAVES_PER_BLOCK][D];
    __shared__ float s_m[WAVES_PER_BLOCK];
    __shared__ float s_l[WAVES_PER_BLOCK];

    *reinterpret_cast<float4*>(&s_acc[wave][lane * 4]) = acc;
    if (lane == 0) { s_m[wave] = m; s_l[wave] = l; }
    __syncthreads();

    if (wave == 0) {
        const float M = fmaxf(fmaxf(s_m[0], s_m[1]), fmaxf(s_m[2], s_m[3]));
        float4 a = {0.0f, 0.0f, 0.0f, 0.0f};
        float  L = 0.0f;
        #pragma unroll
        for (int wv = 0; wv < WAVES_PER_BLOCK; ++wv) {
            const float e = __expf(s_m[wv] - M);
            const float4 aw = *reinterpret_cast<const float4*>(&s_acc[wv][lane * 4]);
            a.x += e * aw.x; a.y += e * aw.y; a.z += e * aw.z; a.w += e * aw.w;
            L += e * s_l[wv];
        }
        float* pacc = ws + (size_t)blk * D;
        *reinterpret_cast<float4*>(pacc + lane * 4) = a;
        if (lane == 0) {
            float* ml = ws + (size_t)nblk_total * D;
            ml[blk * 2 + 0] = M;
            ml[blk * 2 + 1] = L;
        }
    }
}

// Kernel 2: combine P partials per batch, normalize, write out.
__global__ __launch_bounds__(BLOCK) void attn_combine(
    const float* __restrict__ ws,
    float* __restrict__ out,
    int P, int nblk_total)
{
    const int b = blockIdx.x;
    const int d = threadIdx.x;
    const float* __restrict__ ml = ws + (size_t)nblk_total * D;

    float M = -INFINITY;
    for (int i = 0; i < P; ++i)
        M = fmaxf(M, ml[(b * P + i) * 2 + 0]);

    float a = 0.0f, L = 0.0f;
    for (int i = 0; i < P; ++i) {
        const int blk = b * P + i;
        const float e = __expf(ml[blk * 2 + 0] - M);
        a += e * ws[(size_t)blk * D + d];
        L += e * ml[blk * 2 + 1];
    }
    out[b * D + d] = a / L;
}

extern "C" void kernel_launch(void* const* d_in, const int* in_sizes, int n_in,
                              void* d_out, int out_size, void* d_ws, size_t ws_size,
                              hipStream_t stream) {
    const float* enc = (const float*)d_in[0];
    const float* dec = (const float*)d_in[1];
    float* out = (float*)d_out;
    float* ws  = (float*)d_ws;

    const int B = in_sizes[1] / D;              // dec is [B, D]
    const int T = in_sizes[0] / in_sizes[1];    // enc is [B, T, D]

    // P chunks per batch; shrink if workspace is small.
    int P = 64;
    while (P > 1 && ((size_t)B * P * (D + 2) * sizeof(float)) > ws_size) P >>= 1;
    // Also require T divisible by P*WAVES_PER_BLOCK.
    while (P > 1 && (T % (P * WAVES_PER_BLOCK) != 0)) P >>= 1;

    const int nblk = B * P;
    attn_partial<<<nblk, BLOCK, 0, stream>>>(enc, dec, ws, T, P, nblk);
    attn_combine<<<B, BLOCK, 0, stream>>>(ws, out, P, nblk);
}

// Round 2
// 67.581 us; speedup vs baseline: 1.0124x; 1.0124x over previous
//
#include <hip/hip_runtime.h>
#include <math.h>

// Luong attention fused single-pass:
//   scores[b,t] = dec[b] . enc[b,t,:]   (D=256)
//   align = softmax_T(scores)
//   out[b,:] = sum_t align[b,t] * enc[b,t,:]
// Online-softmax so enc is read exactly ONCE (268 MB -> ~40us roofline).
// R1: row-batch of 4 — 4 loads in flight/wave, 4x shorter serial chain,
//     exp count 1.25/row instead of 2/row.

#define WAVES_PER_BLOCK 4
#define BLOCK 256
#define D 256
#define RBATCH 4

// Kernel 1: per-(batch,chunk) partial with online softmax.
// ws layout: acc[B*P][256] floats, then interleaved (m,l)[B*P][2].
__global__ __launch_bounds__(BLOCK) void attn_partial(
    const float* __restrict__ enc,   // [B,T,D]
    const float* __restrict__ dec,   // [B,D]
    float* __restrict__ ws,
    int T, int P, int nblk_total)
{
    const int blk   = blockIdx.x;
    const int b     = blk / P;
    const int chunk = blk % P;
    const int tid   = threadIdx.x;
    const int wave  = tid >> 6;
    const int lane  = tid & 63;

    const int rows_per_block = T / P;
    const int rows_per_wave  = rows_per_block / WAVES_PER_BLOCK;
    const int t0 = chunk * rows_per_block + wave * rows_per_wave;

    const float* __restrict__ encb = enc + (size_t)b * T * D;

    // dec fragment for this lane's 4 columns (reused every row)
    const float4 dq = *reinterpret_cast<const float4*>(dec + b * D + lane * 4);

    float  m = -INFINITY;
    float  l = 0.0f;
    float4 acc = {0.0f, 0.0f, 0.0f, 0.0f};

    #pragma unroll 2
    for (int r = 0; r < rows_per_wave; r += RBATCH) {
        const float* base = encb + (size_t)(t0 + r) * D + lane * 4;
        const float4 x0 = *reinterpret_cast<const float4*>(base);
        const float4 x1 = *reinterpret_cast<const float4*>(base + D);
        const float4 x2 = *reinterpret_cast<const float4*>(base + 2 * D);
        const float4 x3 = *reinterpret_cast<const float4*>(base + 3 * D);

        float p0 = dq.x * x0.x + dq.y * x0.y + dq.z * x0.z + dq.w * x0.w;
        float p1 = dq.x * x1.x + dq.y * x1.y + dq.z * x1.z + dq.w * x1.w;
        float p2 = dq.x * x2.x + dq.y * x2.y + dq.z * x2.z + dq.w * x2.w;
        float p3 = dq.x * x3.x + dq.y * x3.y + dq.z * x3.z + dq.w * x3.w;

        // 4 independent 64-lane butterflies (pipelined, chains overlap)
        #pragma unroll
        for (int off = 32; off >= 1; off >>= 1) {
            p0 += __shfl_xor(p0, off, 64);
            p1 += __shfl_xor(p1, off, 64);
            p2 += __shfl_xor(p2, off, 64);
            p3 += __shfl_xor(p3, off, 64);
        }

        // one online-softmax update for the 4 rows
        const float mn    = fmaxf(fmaxf(fmaxf(p0, p1), fmaxf(p2, p3)), m);
        const float scale = __expf(m - mn);   // 0 when m == -inf
        const float w0 = __expf(p0 - mn);
        const float w1 = __expf(p1 - mn);
        const float w2 = __expf(p2 - mn);
        const float w3 = __expf(p3 - mn);

        acc.x = fmaf(w3, x3.x, fmaf(w2, x2.x, fmaf(w1, x1.x, fmaf(w0, x0.x, acc.x * scale))));
        acc.y = fmaf(w3, x3.y, fmaf(w2, x2.y, fmaf(w1, x1.y, fmaf(w0, x0.y, acc.y * scale))));
        acc.z = fmaf(w3, x3.z, fmaf(w2, x2.z, fmaf(w1, x1.z, fmaf(w0, x0.z, acc.z * scale))));
        acc.w = fmaf(w3, x3.w, fmaf(w2, x2.w, fmaf(w1, x1.w, fmaf(w0, x0.w, acc.w * scale))));
        l = fmaf(l, scale, w0 + w1 + w2 + w3);
        m = mn;
    }

    // combine the 4 waves' partials in LDS -> one partial per block
    __shared__ float s_acc[WAVES_PER_BLOCK][D];
    __shared__ float s_m[WAVES_PER_BLOCK];
    __shared__ float s_l[WAVES_PER_BLOCK];

    *reinterpret_cast<float4*>(&s_acc[wave][lane * 4]) = acc;
    if (lane == 0) { s_m[wave] = m; s_l[wave] = l; }
    __syncthreads();

    if (wave == 0) {
        const float M = fmaxf(fmaxf(s_m[0], s_m[1]), fmaxf(s_m[2], s_m[3]));
        float4 a = {0.0f, 0.0f, 0.0f, 0.0f};
        float  L = 0.0f;
        #pragma unroll
        for (int wv = 0; wv < WAVES_PER_BLOCK; ++wv) {
            const float e = __expf(s_m[wv] - M);
            const float4 aw = *reinterpret_cast<const float4*>(&s_acc[wv][lane * 4]);
            a.x += e * aw.x; a.y += e * aw.y; a.z += e * aw.z; a.w += e * aw.w;
            L += e * s_l[wv];
        }
        float* pacc = ws + (size_t)blk * D;
        *reinterpret_cast<float4*>(pacc + lane * 4) = a;
        if (lane == 0) {
            float* ml = ws + (size_t)nblk_total * D;
            ml[blk * 2 + 0] = M;
            ml[blk * 2 + 1] = L;
        }
    }
}

// Kernel 2: combine P partials per batch, normalize, write out.
__global__ __launch_bounds__(BLOCK) void attn_combine(
    const float* __restrict__ ws,
    float* __restrict__ out,
    int P, int nblk_total)
{
    const int b = blockIdx.x;
    const int d = threadIdx.x;
    const float* __restrict__ ml = ws + (size_t)nblk_total * D;

    float M = -INFINITY;
    for (int i = 0; i < P; ++i)
        M = fmaxf(M, ml[(b * P + i) * 2 + 0]);

    float a = 0.0f, L = 0.0f;
    for (int i = 0; i < P; ++i) {
        const int blk = b * P + i;
        const float e = __expf(ml[blk * 2 + 0] - M);
        a += e * ws[(size_t)blk * D + d];
        L += e * ml[blk * 2 + 1];
    }
    out[b * D + d] = a / L;
}

extern "C" void kernel_launch(void* const* d_in, const int* in_sizes, int n_in,
                              void* d_out, int out_size, void* d_ws, size_t ws_size,
                              hipStream_t stream) {
    const float* enc = (const float*)d_in[0];
    const float* dec = (const float*)d_in[1];
    float* out = (float*)d_out;
    float* ws  = (float*)d_ws;

    const int B = in_sizes[1] / D;              // dec is [B, D]
    const int T = in_sizes[0] / in_sizes[1];    // enc is [B, T, D]

    // P chunks per batch; shrink if workspace is small or shape not divisible.
    int P = 64;
    while (P > 1 && ((size_t)B * P * (D + 2) * sizeof(float)) > ws_size) P >>= 1;
    while (P > 1 && (T % (P * WAVES_PER_BLOCK * RBATCH) != 0)) P >>= 1;

    const int nblk = B * P;
    attn_partial<<<nblk, BLOCK, 0, stream>>>(enc, dec, ws, T, P, nblk);
    attn_combine<<<B, BLOCK, 0, stream>>>(ws, out, P, nblk);
}